// Round 2
// baseline (403.621 us; speedup 1.0000x reference)
//
#include <hip/hip_runtime.h>
#include <stdint.h>

// out[bm,q,h] = sum_k s[bm,q,k] * v[bm,k,h]
// bm=64, QT=KVT=1024, H=64, fp32 in/out. Memory-bound: ~302 MB @ ~6.6 TB/s => ~48us floor.
//
// Two-kernel structure:
//  1) vtrans_kernel: one-shot transpose+cvt of v (16 MB fp32) into an 8 MB bf16
//     fragment-layout buffer vtf[bm][ks][nt][lane][8] in d_ws. Removes the 16x
//     redundant per-q-block transpose (16 scalar loads + 16 packs + LDS round
//     trip + barrier per tile) from the hot loop.
//  2) svbmm_kernel: LDS-free, barrier-free pure stream. A-fragments load direct
//     from global s (8 contiguous fp32/lane matches the 16x16x32 A layout
//     row=lane&15, k=(lane>>4)*8+j) and pack to bf16 in-register; B-fragments are
//     single coalesced 16B/lane loads from vtf (L1/L2-hot). 1-deep register
//     prefetch; 16 waves/CU in flight saturate HBM.

typedef __bf16    bf16x8 __attribute__((ext_vector_type(8)));
typedef float     f32x4  __attribute__((ext_vector_type(4)));
typedef uint32_t  u32x4  __attribute__((ext_vector_type(4)));

#define QTDIM 1024
#define KVDIM 1024
#define HDIM  64
#define QTILE 64
#define NKS   (KVDIM / 32)   // 32 k-steps of K=32
#define THREADS 256

// truncate two f32 to bf16, pack (hi<<16)|lo in one v_perm_b32
__device__ __forceinline__ uint32_t pack_bf16_2(float lo, float hi) {
    union { float f; uint32_t u; } a, b;
    a.f = lo; b.f = hi;
    return __builtin_amdgcn_perm(b.u, a.u, 0x07060302u);
}

__device__ __forceinline__ bf16x8 as_bf16x8(u32x4 u) {
    union { u32x4 u; bf16x8 b; } c; c.u = u; return c.b;
}

// ---------------- pre-pass: v[bm][k][h] fp32 -> vtf[bm][ks][nt][lane][8] bf16 ----
// vtf element for (bm, ks, nt, lane): v[bm][ks*32 + (lane>>4)*8 + j][nt*16 + (lane&15)], j=0..7
// size = 64 * 32 * 4 * 64 * 16 B = 8 MB
__global__ __launch_bounds__(256) void vtrans_kernel(
    const float* __restrict__ v, uint16_t* __restrict__ vtf)
{
    __shared__ float lds[64][68];    // 64 k-rows x 64 h (+4 pad), 16B-aligned rows

    const int tid = threadIdx.x;
    const int kb  = blockIdx.x;      // 16 blocks of 64 k-rows
    const int bm  = blockIdx.y;

    const float* vp = v + ((size_t)bm * KVDIM + (size_t)kb * 64) * HDIM;

    // coalesced load of the 64x64 fp32 tile (1024 float4s, 4 per thread)
    #pragma unroll
    for (int i = 0; i < 4; ++i) {
        int f = i * 256 + tid;             // float4 index
        int r = f >> 4, c4 = f & 15;
        float4 val = *(const float4*)(vp + r * HDIM + c4 * 4);
        *(float4*)&lds[r][c4 * 4] = val;
    }
    __syncthreads();

    const int lane = tid & 63;
    const int w    = tid >> 6;            // wave == nt
    const int lrow = lane & 15;
    const int quad = lane >> 4;
    const int col  = w * 16 + lrow;       // h index

    #pragma unroll
    for (int t = 0; t < 2; ++t) {         // two k-steps per 64-row block
        const int ks   = kb * 2 + t;
        const int kloc = t * 32 + quad * 8;
        u32x4 pk;
        pk.x = pack_bf16_2(lds[kloc + 0][col], lds[kloc + 1][col]);
        pk.y = pack_bf16_2(lds[kloc + 2][col], lds[kloc + 3][col]);
        pk.z = pack_bf16_2(lds[kloc + 4][col], lds[kloc + 5][col]);
        pk.w = pack_bf16_2(lds[kloc + 6][col], lds[kloc + 7][col]);
        size_t off = ((((size_t)bm * 32 + ks) * 4 + w) * 64 + lane) * 8; // uint16 units
        *(u32x4*)&vtf[off] = pk;
    }
}

// ---------------- main: LDS-free, barrier-free streaming MFMA ----------------
__global__ __launch_bounds__(THREADS, 4) void svbmm_kernel(
    const float* __restrict__ s, const uint16_t* __restrict__ vtf,
    float* __restrict__ out)
{
    const int tid  = threadIdx.x;
    const int bm   = blockIdx.y;
    const int q0   = blockIdx.x * QTILE;
    const int wave = tid >> 6;
    const int lane = tid & 63;
    const int lrow = lane & 15;
    const int quad = lane >> 4;

    // A stream: lane reads s[q0 + wave*16 + lrow][ks*32 + quad*8 .. +8]
    const float* __restrict__ sp =
        s + ((size_t)bm * QTDIM + q0 + wave * 16 + lrow) * KVDIM + quad * 8;
    // B stream: vtf[bm][ks][nt][lane], nt stride = 512 u16 (1024 B), ks stride = 2048 u16
    const uint16_t* __restrict__ vp =
        vtf + ((size_t)bm * 32 * 4 * 64 + lane) * 8;

    f32x4 acc[4];
    #pragma unroll
    for (int nt = 0; nt < 4; ++nt)
        acc[nt] = (f32x4){0.f, 0.f, 0.f, 0.f};

    auto step = [&](float4 f0, float4 f1, u32x4 b0, u32x4 b1, u32x4 b2, u32x4 b3) {
        u32x4 au;
        au.x = pack_bf16_2(f0.x, f0.y);
        au.y = pack_bf16_2(f0.z, f0.w);
        au.z = pack_bf16_2(f1.x, f1.y);
        au.w = pack_bf16_2(f1.z, f1.w);
        bf16x8 a = as_bf16x8(au);
        acc[0] = __builtin_amdgcn_mfma_f32_16x16x32_bf16(a, as_bf16x8(b0), acc[0], 0, 0, 0);
        acc[1] = __builtin_amdgcn_mfma_f32_16x16x32_bf16(a, as_bf16x8(b1), acc[1], 0, 0, 0);
        acc[2] = __builtin_amdgcn_mfma_f32_16x16x32_bf16(a, as_bf16x8(b2), acc[2], 0, 0, 0);
        acc[3] = __builtin_amdgcn_mfma_f32_16x16x32_bf16(a, as_bf16x8(b3), acc[3], 0, 0, 0);
    };

    // prologue: stage ks=0
    float4 pa0 = *(const float4*)(sp);
    float4 pa1 = *(const float4*)(sp + 4);
    u32x4  pb0 = *(const u32x4*)(vp);
    u32x4  pb1 = *(const u32x4*)(vp + 512);
    u32x4  pb2 = *(const u32x4*)(vp + 1024);
    u32x4  pb3 = *(const u32x4*)(vp + 1536);

    #pragma unroll 4
    for (int ks = 0; ks < NKS - 1; ++ks) {
        const float*    sn = sp + (size_t)(ks + 1) * 32;
        const uint16_t* vn = vp + (size_t)(ks + 1) * 2048;

        float4 ca0 = pa0, ca1 = pa1;
        u32x4  cb0 = pb0, cb1 = pb1, cb2 = pb2, cb3 = pb3;

        // issue next k-step's loads before consuming current (1-deep pipeline)
        pa0 = *(const float4*)(sn);
        pa1 = *(const float4*)(sn + 4);
        pb0 = *(const u32x4*)(vn);
        pb1 = *(const u32x4*)(vn + 512);
        pb2 = *(const u32x4*)(vn + 1024);
        pb3 = *(const u32x4*)(vn + 1536);

        step(ca0, ca1, cb0, cb1, cb2, cb3);
    }
    step(pa0, pa1, pb0, pb1, pb2, pb3);   // last k-step

    // epilogue: D row = quad*4 + r, col = lane&15 (m89/m91-verified layout)
    float* __restrict__ op = out + ((size_t)bm * QTDIM + q0 + wave * 16) * HDIM;
    #pragma unroll
    for (int nt = 0; nt < 4; ++nt) {
        #pragma unroll
        for (int r = 0; r < 4; ++r) {
            op[(quad * 4 + r) * HDIM + nt * 16 + lrow] = acc[nt][r];
        }
    }
}

extern "C" void kernel_launch(void* const* d_in, const int* in_sizes, int n_in,
                              void* d_out, int out_size, void* d_ws, size_t ws_size,
                              hipStream_t stream) {
    const float* s = (const float*)d_in[0];
    const float* v = (const float*)d_in[1];
    float* out = (float*)d_out;
    const int BM = in_sizes[0] / (QTDIM * KVDIM);  // 64

    uint16_t* vtf = (uint16_t*)d_ws;               // needs 8 MB of workspace

    dim3 gridT(KVDIM / 64, BM);                    // 16 x 64 tiny transpose blocks
    vtrans_kernel<<<gridT, 256, 0, stream>>>(v, vtf);

    dim3 grid(QTDIM / QTILE, BM);                  // 16 x 64 = 1024 blocks = 4/CU
    svbmm_kernel<<<grid, THREADS, 0, stream>>>(s, vtf, out);
}

// Round 5
// 395.308 us; speedup vs baseline: 1.0210x; 1.0210x over previous
//
#include <hip/hip_runtime.h>
#include <stdint.h>

// out[bm,q,h] = sum_k s[bm,q,k] * v[bm,k,h]
// bm=64, QT=KVT=1024, H=64, fp32 in/out. Memory-bound: ~302 MB @ ~6.6 TB/s => ~48us floor.
//
// Round-0 proven structure (59.5us kernel) + hoisted v-transpose:
//  1) vtrans_kernel (LDS-free): one-shot transpose+cvt of v into an 8 MB bf16
//     fragment-layout buffer vtf[bm][ks][nt][lane][8] in d_ws.
//  2) svbmm_kernel: identical s-path to round 0 (coalesced float4 stage -> pack
//     -> LDS double-buffer -> single barrier -> global prefetch issued after the
//     barrier so it survives the drain). v-path replaced: B-fragments are single
//     coalesced 16B/lane loads from L2-hot vtf, issued at the top of the MFMA
//     phase BEFORE the s-prefetch (vmcnt retires in issue order, so waiting for
//     b costs vmcnt(4) and leaves the s-prefetch in flight).
//
// R4 bugfix: vp's bm stride was 8192 u16 (dropped *8) -> read wrong bm's
// fragments for bm>=1, absmax 232. Restored round-2's (bm*32*4*64 + lane)*8.

typedef __bf16    bf16x8 __attribute__((ext_vector_type(8)));
typedef float     f32x4  __attribute__((ext_vector_type(4)));
typedef uint32_t  u32x4  __attribute__((ext_vector_type(4)));

#define QTDIM 1024
#define KVDIM 1024
#define HDIM  64
#define QTILE 64
#define BK    64
#define NK    (KVDIM / BK)   // 16
#define SSTR  72             // LDS row stride (bf16 elems); 144 B rows, 16B-aligned
#define THREADS 256

// truncate two f32 to bf16, pack (hi<<16)|lo in one v_perm_b32
__device__ __forceinline__ uint32_t pack_bf16_2(float lo, float hi) {
    union { float f; uint32_t u; } a, b;
    a.f = lo; b.f = hi;
    return __builtin_amdgcn_perm(b.u, a.u, 0x07060302u);
}

__device__ __forceinline__ bf16x8 as_bf16x8(u32x4 u) {
    union { u32x4 u; bf16x8 b; } c; c.u = u; return c.b;
}

// ---------------- pre-pass: v[bm][k][h] fp32 -> vtf[bm][ks][nt][lane][8] bf16 ----
// vtf element for (bm, ks, nt, lane)[j] = v[ks*32 + (lane>>4)*8 + j][nt*16 + (lane&15)]
// size = 64 * 32 * 4 * 64 * 16 B = 8 MB. LDS-free: scalar k-column gather
// (4 rows x 64B contiguous per instruction across the wave) + coalesced 16B store.
__global__ __launch_bounds__(256) void vtrans_kernel(
    const float* __restrict__ v, uint16_t* __restrict__ vtf)
{
    const int tid  = threadIdx.x;
    const int lane = tid & 63;
    const int w    = tid >> 6;          // wave == nt
    const int ks   = blockIdx.x;        // 0..31
    const int bm   = blockIdx.y;        // 0..63
    const int lrow = lane & 15;
    const int quad = lane >> 4;

    const float* vp = v + ((size_t)bm * KVDIM + ks * 32 + quad * 8) * HDIM
                        + w * 16 + lrow;
    float f[8];
    #pragma unroll
    for (int j = 0; j < 8; ++j) f[j] = vp[j * HDIM];

    u32x4 pk;
    pk.x = pack_bf16_2(f[0], f[1]);
    pk.y = pack_bf16_2(f[2], f[3]);
    pk.z = pack_bf16_2(f[4], f[5]);
    pk.w = pack_bf16_2(f[6], f[7]);

    size_t off = ((((size_t)bm * 32 + ks) * 4 + w) * 64 + lane) * 8;  // u16 units
    *(u32x4*)&vtf[off] = pk;
}

// ---------------- main: round-0 pipeline, v-path from vtf ----------------
__global__ __launch_bounds__(THREADS, 4) void svbmm_kernel(
    const float* __restrict__ s, const uint16_t* __restrict__ vtf,
    float* __restrict__ out)
{
    // double-buffered bf16 s-tile [64][72]
    __shared__ uint16_t s_sm[2][QTILE * SSTR];   // 2 x 9216 B = 18 KB

    const int tid = threadIdx.x;
    const int bm  = blockIdx.y;
    const int q0  = blockIdx.x * QTILE;

    const float* sp = s   + ((size_t)bm * QTDIM + q0) * (size_t)KVDIM;
    float*       op = out + ((size_t)bm * QTDIM + q0) * (size_t)HDIM;

    // staging assignment (s only)
    const int srow = tid >> 4;          // 0..15 (+16*i, i<4 covers 64 rows)
    const int scol = (tid & 15) << 2;   // float4 col within BK

    float4 sreg[4];

    // prologue: s loads for kt = 0
    {
        const float* sb = sp + srow * KVDIM + scol;
        #pragma unroll
        for (int i = 0; i < 4; ++i)
            sreg[i] = *(const float4*)(sb + i * 16 * KVDIM);
    }

    f32x4 acc[4];
    #pragma unroll
    for (int nt = 0; nt < 4; ++nt)
        acc[nt] = (f32x4){0.f, 0.f, 0.f, 0.f};

    const int wave = tid >> 6;   // wave owns q-rows [wave*16, wave*16+16)
    const int lane = tid & 63;
    const int lrow = lane & 15;
    const int quad = lane >> 4;

    // B stream base: vtf[bm][ks][nt][lane]; u16 units.
    // bm stride = 65536, ks stride = 2048, nt stride = 512, per-kt (2 ks) = 4096.
    const uint16_t* vp = vtf + ((size_t)bm * 32 * 4 * 64 + (size_t)lane) * 8;

    #pragma unroll 2
    for (int kt = 0; kt < NK; ++kt) {
        const int buf = kt & 1;

        // ---- cvt + store s tile kt to LDS (vmcnt waits pipelined per-use) ----
        #pragma unroll
        for (int i = 0; i < 4; ++i) {
            float4 f = sreg[i];
            uint64_t u = (uint64_t)pack_bf16_2(f.x, f.y)
                       | ((uint64_t)pack_bf16_2(f.z, f.w) << 32);
            *(uint64_t*)&s_sm[buf][(srow + i * 16) * SSTR + scol] = u;
        }

        // single barrier: publishes buf, and guarantees buf^1's readers from
        // iter kt-1 are done before iter kt+1 overwrites it. Zero outstanding
        // VMEM here => the implicit vmcnt(0) is free.
        __syncthreads();

        // ---- b loads for tile kt (L2-hot, consumed this phase) issued FIRST,
        //      then the s prefetch for kt+1 (stays in flight across back-edge) ----
        u32x4 b[8];
        {
            const uint16_t* vb = vp + (size_t)kt * 4096;
            #pragma unroll
            for (int kk = 0; kk < 2; ++kk)
                #pragma unroll
                for (int nt = 0; nt < 4; ++nt)
                    b[kk * 4 + nt] = *(const u32x4*)(vb + kk * 2048 + nt * 512);
        }
        if (kt + 1 < NK) {
            const float* sb = sp + srow * KVDIM + (kt + 1) * BK + scol;
            #pragma unroll
            for (int i = 0; i < 4; ++i)
                sreg[i] = *(const float4*)(sb + i * 16 * KVDIM);
        }

        // ---- MFMA on tile kt ----
        #pragma unroll
        for (int kk = 0; kk < 2; ++kk) {
            const int col = kk * 32 + quad * 8;
            bf16x8 a = *(const bf16x8*)&s_sm[buf][(wave * 16 + lrow) * SSTR + col];
            #pragma unroll
            for (int nt = 0; nt < 4; ++nt)
                acc[nt] = __builtin_amdgcn_mfma_f32_16x16x32_bf16(
                    a, as_bf16x8(b[kk * 4 + nt]), acc[nt], 0, 0, 0);
        }
        // no second barrier: next iteration writes buf^1, already safe.
    }

    // ---- epilogue: D layout row = quad*4 + r, col = lane&15 (m89/m91-verified) ----
    #pragma unroll
    for (int nt = 0; nt < 4; ++nt) {
        #pragma unroll
        for (int r = 0; r < 4; ++r) {
            const int row = wave * 16 + quad * 4 + r;
            const int col = nt * 16 + lrow;
            op[row * HDIM + col] = acc[nt][r];
        }
    }
}

extern "C" void kernel_launch(void* const* d_in, const int* in_sizes, int n_in,
                              void* d_out, int out_size, void* d_ws, size_t ws_size,
                              hipStream_t stream) {
    const float* s = (const float*)d_in[0];
    const float* v = (const float*)d_in[1];
    float* out = (float*)d_out;
    const int BM = in_sizes[0] / (QTDIM * KVDIM);  // 64

    uint16_t* vtf = (uint16_t*)d_ws;               // needs 8 MB of workspace

    dim3 gridT(KVDIM / 32, BM);                    // 32 x 64 = 2048 tiny blocks
    vtrans_kernel<<<gridT, 256, 0, stream>>>(v, vtf);

    dim3 grid(QTDIM / QTILE, BM);                  // 16 x 64 = 1024 blocks = 4/CU
    svbmm_kernel<<<grid, THREADS, 0, stream>>>(s, vtf, out);
}